// Round 5
// baseline (383.469 us; speedup 1.0000x reference)
//
#include <hip/hip_runtime.h>
#include <stdint.h>

#define BS 4
#define NN 1024
#define GD 6
#define CIN 256
#define NH 8
#define DH 32
#define HID 16
#define MCS 64

#define PG_ELEMS (BS*NN*NN*GD)                 // 25165824
#define OUT_OFF  PG_ELEMS
#define MASK_OFF (PG_ELEMS + BS*NN*CIN)        // 26214400

typedef float vfloat4 __attribute__((ext_vector_type(4)));
typedef float vfloat2 __attribute__((ext_vector_type(2)));
typedef unsigned vuint4 __attribute__((ext_vector_type(4)));

#if __has_builtin(__builtin_amdgcn_rcpf)
__device__ __forceinline__ float fast_rcp(float x) { return __builtin_amdgcn_rcpf(x); }
#else
__device__ __forceinline__ float fast_rcp(float x) { return 1.0f / x; }
#endif
#if __has_builtin(__builtin_amdgcn_exp2f)
__device__ __forceinline__ float fast_exp2(float x) { return __builtin_amdgcn_exp2f(x); }
#else
__device__ __forceinline__ float fast_exp2(float x) { return exp2f(x); }
#endif
#define LOG2E 1.44269504088896340736f

__device__ __forceinline__ float swishf(float x) {
    return x * fast_rcp(1.0f + fast_exp2(x * -LOG2E));
}

// Fused 4096x256 @ 256x256 + bias GEMM; blockIdx.y selects one of up to 3 (W,b,dst).
template<int RPB>
__global__ __launch_bounds__(256) void gemm3(const float* __restrict__ X,
    const float* __restrict__ W0, const float* __restrict__ B0, float* __restrict__ D0,
    const float* __restrict__ W1, const float* __restrict__ B1, float* __restrict__ D1,
    const float* __restrict__ W2, const float* __restrict__ B2, float* __restrict__ D2)
{
    const float* W; const float* Bv; float* D;
    if (blockIdx.y == 0)      { W = W0; Bv = B0; D = D0; }
    else if (blockIdx.y == 1) { W = W1; Bv = B1; D = D1; }
    else                      { W = W2; Bv = B2; D = D2; }
    const int tid = threadIdx.x;
    const int c4  = tid & 63;
    const int rg  = tid >> 6;
    const int r0  = blockIdx.x * RPB;
    constexpr int RG = RPB / 4;

    __shared__ float xsT[CIN][RPB + 4];
    {
        float tmp[RPB];
        #pragma unroll
        for (int r = 0; r < RPB; ++r) tmp[r] = X[(size_t)(r0 + r)*CIN + tid];
        #pragma unroll
        for (int j = 0; j < RPB/4; ++j)
            *(vfloat4*)&xsT[tid][4*j] = (vfloat4){tmp[4*j+0], tmp[4*j+1], tmp[4*j+2], tmp[4*j+3]};
    }
    __syncthreads();

    vfloat4 acc[RG];
    #pragma unroll
    for (int r = 0; r < RG; ++r) acc[r] = (vfloat4){0.f,0.f,0.f,0.f};
    const vfloat4* W4 = (const vfloat4*)W;
    #pragma unroll 4
    for (int k = 0; k < CIN; ++k) {
        vfloat4 w = W4[(size_t)k*64 + c4];
        if constexpr (RG == 4) {
            vfloat4 xr = *(const vfloat4*)&xsT[k][rg*4];
            acc[0] += xr.x * w;
            acc[1] += xr.y * w;
            acc[2] += xr.z * w;
            acc[3] += xr.w * w;
        } else {
            vfloat2 xr = *(const vfloat2*)&xsT[k][rg*2];
            acc[0] += xr.x * w;
            acc[1] += xr.y * w;
        }
    }
    vfloat4 bb = ((const vfloat4*)Bv)[c4];
    vfloat4* D4 = (vfloat4*)D;
    const size_t rbase = (size_t)(r0 + rg*RG);
    #pragma unroll
    for (int r = 0; r < RG; ++r) D4[(rbase + r)*64 + c4] = acc[r] + bb;
}

// Wave-autonomous attention: ONE WAVE per (query i, batch b). Block = 4 independent
// queries. ZERO __syncthreads -- all sync is implicit wave-internal lgkmcnt.
__global__ __launch_bounds__(256, 4) void attn_topk(
    const float* __restrict__ pg, const int* __restrict__ mask,
    const float* __restrict__ lW1g, const float* __restrict__ lb1g,
    const float* __restrict__ lW2g, const float* __restrict__ lb2g,
    const float* __restrict__ lW3g, const float* __restrict__ lb3g,
    const float* __restrict__ Q, const float* __restrict__ Kc, const float* __restrict__ Vc,
    float* __restrict__ O, float* __restrict__ pg_out, float* __restrict__ mask_out)
{
    const int tid = threadIdx.x;
    const int w = tid >> 6, l = tid & 63;
    const int i = blockIdx.x*4 + w, b = blockIdx.y;

    // per-wave LDS: sc[64*9] f32 (2304 B; select phase aliases hist[256]+ckey[64] u32),
    // nj[64], joff[64]. 2816 B/wave, 11.3 KB/block.
    __shared__ __align__(16) float s_sc[4][576];
    __shared__ __align__(16) int s_nj[4][64];
    __shared__ __align__(16) unsigned s_joff[4][64];
    float* scf = s_sc[w];
    unsigned* hist = (unsigned*)s_sc[w];         // [0..255]
    unsigned* ckey = (unsigned*)s_sc[w] + 256;   // [256..319] candidates / eqlist
    int* nj = s_nj[w];
    unsigned* joff = s_joff[w];

    const int* mrow = mask + b*NN;
    if (l == 0) mask_out[b*NN + i] = mrow[i] ? 1.0f : 0.0f;

    const size_t rowoff = (size_t)(b*NN + i) * (NN*GD);
    const vfloat4* src4 = (const vfloat4*)(pg + rowoff);
    vfloat4* dst4 = (vfloat4*)(pg_out + rowoff);

    // ---- passthrough copy: 24 coalesced quads/lane, NT stores. No barrier ever
    //      waits on these stores (they only must retire by kernel end). ----
    #pragma unroll
    for (int c = 0; c < 3; ++c) {
        vfloat4 t0 = src4[l + 64*(8*c+0)], t1 = src4[l + 64*(8*c+1)];
        vfloat4 t2 = src4[l + 64*(8*c+2)], t3 = src4[l + 64*(8*c+3)];
        vfloat4 t4 = src4[l + 64*(8*c+4)], t5 = src4[l + 64*(8*c+5)];
        vfloat4 t6 = src4[l + 64*(8*c+6)], t7 = src4[l + 64*(8*c+7)];
        __builtin_nontemporal_store(t0, &dst4[l + 64*(8*c+0)]);
        __builtin_nontemporal_store(t1, &dst4[l + 64*(8*c+1)]);
        __builtin_nontemporal_store(t2, &dst4[l + 64*(8*c+2)]);
        __builtin_nontemporal_store(t3, &dst4[l + 64*(8*c+3)]);
        __builtin_nontemporal_store(t4, &dst4[l + 64*(8*c+4)]);
        __builtin_nontemporal_store(t5, &dst4[l + 64*(8*c+5)]);
        __builtin_nontemporal_store(t6, &dst4[l + 64*(8*c+6)]);
        __builtin_nontemporal_store(t7, &dst4[l + 64*(8*c+7)]);
    }
    vfloat4 q4 = ((const vfloat4*)Q)[(size_t)(b*NN + i)*64 + l];

    // ---- keys: lane owns rows 4*(l+64*rg)+0..3 (rg=0..3); reads are L1/L2-warm ----
    const unsigned U30 = __float_as_uint(1e30f);
    unsigned key[16];
    #pragma unroll 2
    for (int rg = 0; rg < 4; ++rg) {
        const int4 mv = ((const int4*)mrow)[l + 64*rg];
        const vfloat4* gp = src4 + 6*(l + 64*rg);
        vfloat4 a0 = gp[0], a1 = gp[1], a2 = gp[2], a3 = gp[3], a4 = gp[4], a5 = gp[5];
        float d0 = a0.x*a0.x + a0.y*a0.y + a0.z*a0.z + a0.w*a0.w + a1.x*a1.x + a1.y*a1.y;
        float d1 = a1.z*a1.z + a1.w*a1.w + a2.x*a2.x + a2.y*a2.y + a2.z*a2.z + a2.w*a2.w;
        float d2 = a3.x*a3.x + a3.y*a3.y + a3.z*a3.z + a3.w*a3.w + a4.x*a4.x + a4.y*a4.y;
        float d3 = a4.z*a4.z + a4.w*a4.w + a5.x*a5.x + a5.y*a5.y + a5.z*a5.z + a5.w*a5.w;
        key[rg*4+0] = __float_as_uint(mv.x ? d0 : 1e30f);
        key[rg*4+1] = __float_as_uint(mv.y ? d1 : 1e30f);
        key[rg*4+2] = __float_as_uint(mv.z ? d2 : 1e30f);
        key[rg*4+3] = __float_as_uint(mv.w ? d3 : 1e30f);
    }

    // ---- wave-local radix select with early exit (port of the verified block code) ----
    const unsigned long long ltm = ((unsigned long long)1 << l) - 1;
    unsigned prefix = 0, T = 0;
    int need = MCS, needT = 0;
    #pragma unroll 1
    for (int level = 0; level < 4; ++level) {
        const int shift = 24 - 8*level;
        ((vuint4*)hist)[l] = (vuint4){0,0,0,0};     // zero 256 bins (wave-ordered)
        const unsigned pmaskhi = (level == 0) ? 0u : (0xFFFFFFFFu << (shift + 8));
        // ballot-clustered histogram: one plain LDS += per distinct digit (leaders only)
        #pragma unroll
        for (int r = 0; r < 16; ++r) {
            const bool act = (level == 0) ? true : ((key[r] & pmaskhi) == prefix);
            const unsigned d = (key[r] >> shift) & 0xFFu;
            unsigned long long todo = __ballot(act);
            while (todo) {
                int leader = (int)(__ffsll((unsigned long long)todo) - 1);
                unsigned dl = __shfl(d, leader);
                unsigned long long mm = __ballot(act && d == dl);
                if (l == leader) hist[dl] += (unsigned)__popcll(mm);
                todo &= ~mm;
            }
        }
        // scan 256 bins: lane l holds bins 4l..4l+3
        vuint4 bb = ((const vuint4*)hist)[l];
        unsigned own = bb.x + bb.y + bb.z + bb.w;
        unsigned v = own;
        #pragma unroll
        for (int off = 1; off < 64; off <<= 1) {
            unsigned nv = __shfl_up(v, off);
            if (l >= off) v += nv;
        }
        const unsigned excl = v - own;
        const unsigned un = (unsigned)need;
        unsigned long long hb = __ballot(excl < un && un <= v);
        int hl = (int)__ffsll(hb) - 1;
        // within-group pick (computed on all lanes, broadcast from the hit lane)
        unsigned c0 = excl + bb.x, c1 = c0 + bb.y, c2 = c1 + bb.z;
        int t    = (un <= c0) ? 0 : (un <= c1) ? 1 : (un <= c2) ? 2 : 3;
        unsigned ndl = un - ((t == 0) ? excl : (t == 1) ? c0 : (t == 2) ? c1 : c2);
        unsigned bnl = (t == 0) ? bb.x : (t == 1) ? bb.y : (t == 2) ? bb.z : bb.w;
        unsigned binl = 4u*l + (unsigned)t;
        unsigned bin = __shfl(binl, hl);
        need = (int)__shfl(ndl, hl);
        const int bincnt = (int)__shfl(bnl, hl);
        prefix |= bin << shift;
        if (level == 3) { T = prefix; needT = need; break; }
        if (bincnt <= 64) {
            // gather the bin's candidates via ballot-prefix scatter, rank exactly
            const unsigned pm = 0xFFFFFFFFu << shift;
            unsigned cb = 0;
            #pragma unroll
            for (int r = 0; r < 16; ++r) {
                bool mt = (key[r] & pm) == prefix;
                unsigned long long mm = __ballot(mt);
                if (mt) ckey[cb + (unsigned)__popcll(mm & ltm)] = key[r];
                cb += (unsigned)__popcll(mm);
            }
            unsigned myk = (l < bincnt) ? ckey[l] : 0xFFFFFFFFu;
            int rk = 0, ee = 0;
            for (int t2 = 0; t2 < bincnt; ++t2) {
                unsigned kt = __shfl(myk, t2);
                rk += (kt <  myk) ? 1 : 0;
                ee += (kt == myk) ? 1 : 0;
            }
            unsigned long long sb = __ballot((l < bincnt) && rk < need && need <= rk + ee);
            int sl2 = (int)__ffsll(sb) - 1;
            T = __shfl(myk, sl2);
            needT = __shfl(need - rk, sl2);
            break;
        }
    }

    // ---- compaction via ballot-prefix (atomic-free); ties captured in j-order ----
    unsigned cnt = 0, ec = 0;
    #pragma unroll
    for (int r = 0; r < 16; ++r) {
        const int j = 4*(l + 64*(r >> 2)) + (r & 3);
        const unsigned kk = key[r];
        bool s1 = kk < T;
        unsigned long long m1 = __ballot(s1);
        if (s1) nj[cnt + (unsigned)__popcll(m1 & ltm)] = j | ((kk == U30) ? (int)0x80000000 : 0);
        cnt += (unsigned)__popcll(m1);
        bool s2 = kk == T;
        unsigned long long m2 = __ballot(s2);
        if (s2) {
            unsigned e = ec + (unsigned)__popcll(m2 & ltm);
            if (e < 64) ckey[e] = (unsigned)j;
        }
        ec += (unsigned)__popcll(m2);
    }
    const int cbase = (int)cnt;
    if (l == 0) {
        int ecc = (int)ec; if (ecc > 64) ecc = 64;
        for (int s2 = 0; s2 < needT; ++s2) {
            int bi = -1, bj = 0x7FFFFFFF;
            for (int e = 0; e < ecc; ++e) {
                int jj = (int)ckey[e];
                if (jj < bj) { bj = jj; bi = e; }
            }
            if (bi >= 0) {
                ckey[bi] = 0x7FFFFFFFu;
                nj[cbase + s2] = bj | (mrow[bj] ? 0 : (int)0x80000000);
            }
        }
    }

    // ---- slot l: row offset + g re-gather (L2-warm, 24 B) feeds THIS lane's MLP ----
    const int code = nj[l];
    const int jm = code & 0x7FFFFFFF;
    joff[l] = ((unsigned)(b*NN + jm)) << 6;
    const float* gp2 = pg + rowoff + (size_t)jm * 6;
    vfloat2 g01 = *(const vfloat2*)gp2;
    vfloat2 g23 = *(const vfloat2*)(gp2 + 2);
    vfloat2 g45 = *(const vfloat2*)(gp2 + 4);
    float gv[GD] = { g01.x, g01.y, g23.x, g23.y, g45.x, g45.y };

    // ---- location MLP: lane l = slot m=l, loops all 8 heads (uniform s_load weights) ----
    __builtin_amdgcn_s_setprio(1);
    #pragma unroll 1
    for (int h = 0; h < NH; ++h) {
        const float* W1h = lW1g + h*(GD*HID);
        const float* B1h = lb1g + h*HID;
        const float* W2h = lW2g + h*(HID*HID);
        const float* B2h = lb2g + h*HID;
        const float* W3h = lW3g + h*HID;
        float h1[HID];
        #pragma unroll
        for (int kk = 0; kk < HID; ++kk) {
            float a = B1h[kk];
            #pragma unroll
            for (int g = 0; g < GD; ++g) a += gv[g] * W1h[g*HID + kk];
            h1[kk] = swishf(a);
        }
        float h2[HID];
        #pragma unroll
        for (int ll = 0; ll < HID; ++ll) {
            float a = B2h[ll];
            #pragma unroll
            for (int kk = 0; kk < HID; ++kk) a += h1[kk] * W2h[kk*HID + ll];
            h2[ll] = swishf(a);
        }
        float a3 = lb3g[h];
        #pragma unroll
        for (int kk = 0; kk < HID; ++kk) a3 += h2[kk] * W3h[kk];
        scf[l*9 + h] = (code < 0) ? -1e38f : swishf(a3);
    }

    // ---- feat: lane owns channel quad l (head hh=l>>3); scores captured in packs ----
    const int lr = l & 7, hh = l >> 3;
    q4 *= 0.17677669529663688f;            // fold 1/sqrt(32) into q
    const vfloat4* Kc4 = (const vfloat4*)Kc;
    float pack0 = 0.f, pack1 = 0.f, pack2 = 0.f, pack3 = 0.f,
          pack4 = 0.f, pack5 = 0.f, pack6 = 0.f, pack7 = 0.f;
    #pragma unroll
    for (int mg = 0; mg < 16; ++mg) {
        vuint4 o4 = *(const vuint4*)&joff[4*mg];
        vfloat4 kv0 = Kc4[o4.x + (unsigned)l];
        vfloat4 kv1 = Kc4[o4.y + (unsigned)l];
        vfloat4 kv2 = Kc4[o4.z + (unsigned)l];
        vfloat4 kv3 = Kc4[o4.w + (unsigned)l];
        #define FEAT_RED(KV, RR) do { \
            const int m_ = 4*mg + (RR); \
            float d = q4.x * (KV).x; \
            d = fmaf(q4.y, (KV).y, d); \
            d = fmaf(q4.z, (KV).z, d); \
            d = fmaf(q4.w, (KV).w, d); \
            d += __shfl_xor(d, 1); \
            d += __shfl_xor(d, 2); \
            d += __shfl_xor(d, 4); \
            if (lr == (m_ & 7)) { \
                switch (m_ >> 3) { \
                    case 0: pack0 = d; break; case 1: pack1 = d; break; \
                    case 2: pack2 = d; break; case 3: pack3 = d; break; \
                    case 4: pack4 = d; break; case 5: pack5 = d; break; \
                    case 6: pack6 = d; break; default: pack7 = d; break; \
                } \
            } \
        } while (0)
        FEAT_RED(kv0, 0); FEAT_RED(kv1, 1); FEAT_RED(kv2, 2); FEAT_RED(kv3, 3);
        #undef FEAT_RED
    }
    // merge: lane's 8 cells are (m = 8*mc + lr, h = hh) -- single-writer, 2 lanes/bank
    scf[(8*0 + lr)*9 + hh] += pack0;
    scf[(8*1 + lr)*9 + hh] += pack1;
    scf[(8*2 + lr)*9 + hh] += pack2;
    scf[(8*3 + lr)*9 + hh] += pack3;
    scf[(8*4 + lr)*9 + hh] += pack4;
    scf[(8*5 + lr)*9 + hh] += pack5;
    scf[(8*6 + lr)*9 + hh] += pack6;
    scf[(8*7 + lr)*9 + hh] += pack7;

    // ---- softmax over m (lane = m), per head ----
    #pragma unroll 1
    for (int h = 0; h < NH; ++h) {
        float s = scf[l*9 + h];
        float mx = s;
        #pragma unroll
        for (int off = 32; off; off >>= 1) mx = fmaxf(mx, __shfl_xor(mx, off));
        float e = fast_exp2((s - mx) * LOG2E);
        float sum = e;
        #pragma unroll
        for (int off = 32; off; off >>= 1) sum += __shfl_xor(sum, off);
        scf[l*9 + h] = e * fast_rcp(sum);
    }

    // ---- out: lane accumulates its channel quad over all 64 m; coalesced V rows ----
    {
        const vfloat4* Vc4 = (const vfloat4*)Vc;
        vfloat4 acc = (vfloat4){0.f,0.f,0.f,0.f};
        #pragma unroll
        for (int mg = 0; mg < 16; ++mg) {
            vuint4 o4 = *(const vuint4*)&joff[4*mg];
            vfloat4 v0 = Vc4[o4.x + (unsigned)l];
            vfloat4 v1 = Vc4[o4.y + (unsigned)l];
            vfloat4 v2 = Vc4[o4.z + (unsigned)l];
            vfloat4 v3 = Vc4[o4.w + (unsigned)l];
            float a0 = scf[(4*mg + 0)*9 + hh];
            float a1 = scf[(4*mg + 1)*9 + hh];
            float a2 = scf[(4*mg + 2)*9 + hh];
            float a3 = scf[(4*mg + 3)*9 + hh];
            acc += a0 * v0;
            acc += a1 * v1;
            acc += a2 * v2;
            acc += a3 * v3;
        }
        __builtin_amdgcn_s_setprio(0);
        ((vfloat4*)O)[(size_t)(b*NN + i)*64 + l] = acc;
    }
}

extern "C" void kernel_launch(void* const* d_in, const int* in_sizes, int n_in,
                              void* d_out, int out_size, void* d_ws, size_t ws_size,
                              hipStream_t stream) {
    const float* pg   = (const float*)d_in[0];
    const float* x    = (const float*)d_in[1];
    const int*   mask = (const int*)d_in[2];
    const float* lW1  = (const float*)d_in[3];
    const float* lb1  = (const float*)d_in[4];
    const float* lW2  = (const float*)d_in[5];
    const float* lb2  = (const float*)d_in[6];
    const float* lW3  = (const float*)d_in[7];
    const float* lb3  = (const float*)d_in[8];
    const float* Wq   = (const float*)d_in[9];
    const float* bq   = (const float*)d_in[10];
    const float* Wk   = (const float*)d_in[11];
    const float* bk   = (const float*)d_in[12];
    const float* Wv   = (const float*)d_in[13];
    const float* bv   = (const float*)d_in[14];
    const float* Wo   = (const float*)d_in[15];
    const float* bo   = (const float*)d_in[16];

    float* out = (float*)d_out;
    float* Q  = (float*)d_ws;
    float* Kc = Q  + (size_t)BS*NN*CIN;
    float* Vc = Kc + (size_t)BS*NN*CIN;
    float* O  = Vc + (size_t)BS*NN*CIN;

    // QKV projections (z = 0,1,2)
    gemm3<16><<<dim3(BS*NN/16, 3), 256, 0, stream>>>(x, Wq, bq, Q, Wk, bk, Kc, Wv, bv, Vc);
    // top-k + attention: one wave per query, 4 queries/block, zero barriers
    attn_topk<<<dim3(NN/4, BS), 256, 0, stream>>>(pg, mask, lW1, lb1, lW2, lb2, lW3, lb3,
                                                  Q, Kc, Vc, O, out, out + MASK_OFF);
    // output projection: 8 rows/block -> 512 blocks -> 2 blocks/CU
    gemm3<8><<<dim3(BS*NN/8, 1), 256, 0, stream>>>(O, Wo, bo, out + OUT_OFF,
                                                   Wo, bo, out + OUT_OFF,
                                                   Wo, bo, out + OUT_OFF);
}